// Round 10
// baseline (1104.632 us; speedup 1.0000x reference)
//
#include <hip/hip_runtime.h>

#define T_STEPS 800
#define NBATCH  32
#define SST     1024
#define ROW     5120   // SST * 5 floats per (t, n) row
#define DEPTH   5      // register pipeline depth (800 % 5 == 0)

#define PIN() __builtin_amdgcn_sched_barrier(0)

__device__ __forceinline__ float lse5(float v0, float v1, float v2, float v3, float v4) {
  float m = fmaxf(fmaxf(fmaxf(v0, v1), fmaxf(v2, v3)), v4);
  float s = __expf(v0 - m) + __expf(v1 - m) + __expf(v2 - m) +
            __expf(v3 - m) + __expf(v4 - m);
  return m + __logf(s);
}

// Block barrier draining LDS ops; global loads/stores stay in flight.
__device__ __forceinline__ void barrier_lgkm() {
  asm volatile("s_waitcnt lgkmcnt(0)" ::: "memory");
  __builtin_amdgcn_s_barrier();
  asm volatile("" ::: "memory");
}

// Issue one step's score loads as PLAIN loads (normal vmem path, deep queues).
// Caller wraps this in PIN() fences so the scheduler cannot sink them to the
// use site; the compiler still inserts exact (correct) waitcnts before use.
template <int DIR>
__device__ __forceinline__ void issue(const float* __restrict__ base, int s, int u,
                                      float4 (&vi)[5], float (&si)[4]) {
  const int t = DIR ? (T_STEPS - 1 - s) : s;
  const float* rp = base + (size_t)t * (NBATCH * ROW);
  const float4* r4 = (const float4*)(rp + 20 * u);
#pragma unroll
  for (int m = 0; m < 5; ++m) vi[m] = r4[m];
  if constexpr (DIR) {
#pragma unroll
    for (int j = 0; j < 4; ++j) si[j] = rp[5 * u + 1280 * j];
  }
}

// DIR=0 (fwd): thread u owns states {4u..4u+3}; gathers abuf[u+256k].
// DIR=1 (bwd): thread u owns states {u+256j}; gathers abuf[4u..4u+3].
template <int DIR>
__device__ void scan_run(const float* __restrict__ scores, float* __restrict__ out,
                         float* __restrict__ out0, int n, float (*abuf)[SST]) {
  const int u = threadIdx.x;  // 0..255
  const float* base = scores + (size_t)n * ROW;
  float* outn = out + (size_t)n * (T_STEPS + 1) * SST;
  float* o0n  = out0 + (size_t)n * T_STEPS * ROW;   // fwd only

  float4 v[DEPTH][5];
  float  s5[DEPTH][4];
  float  a[4] = {0.f, 0.f, 0.f, 0.f};

  // Prologue: pin-issue loads for steps 0..DEPTH-1.
  PIN();
#pragma unroll
  for (int i = 0; i < DEPTH; ++i) issue<DIR>(base, i, u, v[i], s5[i]);
  PIN();

  // Init alpha[0]=0 / beta[T]=0.
  {
    const float4 z = {0.f, 0.f, 0.f, 0.f};
    *(float4*)&abuf[0][4 * u] = z;
    const size_t t0 = DIR ? (size_t)T_STEPS : 0;
    ((float4*)(outn + t0 * SST))[u] = z;
  }
  barrier_lgkm();

  for (int p = 0; p < T_STEPS; p += DEPTH) {
#pragma unroll
    for (int i = 0; i < DEPTH; ++i) {
      const int s = p + i;
      const int cur = s & 1;
      const int nxt = cur ^ 1;

      // Consume slot i (row s): compiler-inserted vmcnt wait; loads were
      // issued DEPTH steps ago (~4.5 step-times of slack).
      float fv[20];
#pragma unroll
      for (int m = 0; m < 5; ++m) {
        fv[4 * m + 0] = v[i][m].x; fv[4 * m + 1] = v[i][m].y;
        fv[4 * m + 2] = v[i][m].z; fv[4 * m + 3] = v[i][m].w;
      }

      float4 pv;
      if constexpr (!DIR) {
        pv.x = abuf[cur][u];
        pv.y = abuf[cur][u + 256];
        pv.z = abuf[cur][u + 512];
        pv.w = abuf[cur][u + 768];
      } else {
        pv = *(const float4*)&abuf[cur][4 * u];
      }

      float na[4];
#pragma unroll
      for (int j = 0; j < 4; ++j) {
        float w0, w1, w2, w3, w4;
        if constexpr (!DIR) {
          w0 = fv[5 * j + 0] + a[j];
          w1 = fv[5 * j + 1] + pv.x;
          w2 = fv[5 * j + 2] + pv.y;
          w3 = fv[5 * j + 3] + pv.z;
          w4 = fv[5 * j + 4] + pv.w;
        } else {
          w0 = s5[i][j]       + a[j];
          w1 = fv[1 + j + 0]  + pv.x;
          w2 = fv[1 + j + 5]  + pv.y;
          w3 = fv[1 + j + 10] + pv.z;
          w4 = fv[1 + j + 15] + pv.w;
        }
        na[j] = lse5(w0, w1, w2, w3, w4);
        a[j] = na[j];
      }

      // Publish scan row + abuf; fwd also writes the out0 transpose row
      // straight from the pipeline registers (fire-and-forget stores).
      if constexpr (!DIR) {
        const float4 o = {na[0], na[1], na[2], na[3]};
        ((float4*)(outn + (size_t)(s + 1) * SST))[u] = o;
        *(float4*)&abuf[nxt][4 * u] = o;
        float4* o0 = (float4*)(o0n + (size_t)s * ROW + 20 * u);
#pragma unroll
        for (int m = 0; m < 5; ++m) o0[m] = v[i][m];
      } else {
        const int t = T_STEPS - 1 - s;
#pragma unroll
        for (int j = 0; j < 4; ++j) {
          outn[(size_t)t * SST + u + 256 * j] = na[j];
          abuf[nxt][u + 256 * j] = na[j];
        }
      }

      // Pinned refill of slot i with row s+DEPTH (cannot be sunk).
      if (s + DEPTH < T_STEPS) {
        PIN();
        issue<DIR>(base, s + DEPTH, u, v[i], s5[i]);
        PIN();
      }

      barrier_lgkm();  // abuf[nxt] visible for next step
    }
  }
}

__global__ __launch_bounds__(256, 1) void mega(const float* __restrict__ scores,
                                               float* __restrict__ out0,
                                               float* __restrict__ bwdo,
                                               float* __restrict__ fposts) {
  __shared__ float abuf[2][SST];  // 8 KB: the only LDS
  const int b = blockIdx.x;
  if (b < NBATCH) scan_run<0>(scores, fposts, out0, b, abuf);
  else            scan_run<1>(scores, bwdo,   out0, b - NBATCH, abuf);
}

// One wave per row of 1024: posts = softmax(fwd + bwd), in place over fwd buffer.
__global__ __launch_bounds__(256) void posts_kernel(float* __restrict__ fp,
                                                    const float* __restrict__ bp) {
  const int lane = threadIdx.x & 63;
  const int wid  = threadIdx.x >> 6;
  const size_t row = (size_t)blockIdx.x * 4 + wid;
  float* f = fp + row * SST;
  const float* b = bp + row * SST;

  float x[16];
#pragma unroll
  for (int k = 0; k < 4; ++k) {
    const float4 fv = ((const float4*)f)[lane + 64 * k];
    const float4 bv = ((const float4*)b)[lane + 64 * k];
    x[4 * k + 0] = fv.x + bv.x;
    x[4 * k + 1] = fv.y + bv.y;
    x[4 * k + 2] = fv.z + bv.z;
    x[4 * k + 3] = fv.w + bv.w;
  }
  float m = x[0];
#pragma unroll
  for (int j = 1; j < 16; ++j) m = fmaxf(m, x[j]);
#pragma unroll
  for (int off = 32; off >= 1; off >>= 1) m = fmaxf(m, __shfl_xor(m, off));
  float ssum = 0.0f;
#pragma unroll
  for (int j = 0; j < 16; ++j) { x[j] = __expf(x[j] - m); ssum += x[j]; }
#pragma unroll
  for (int off = 32; off >= 1; off >>= 1) ssum += __shfl_xor(ssum, off);
  const float inv = 1.0f / ssum;
#pragma unroll
  for (int k = 0; k < 4; ++k) {
    float4 o;
    o.x = x[4 * k + 0] * inv;
    o.y = x[4 * k + 1] * inv;
    o.z = x[4 * k + 2] * inv;
    o.w = x[4 * k + 3] * inv;
    ((float4*)f)[lane + 64 * k] = o;
  }
}

extern "C" void kernel_launch(void* const* d_in, const int* in_sizes, int n_in,
                              void* d_out, int out_size, void* d_ws, size_t ws_size,
                              hipStream_t stream) {
  (void)in_sizes; (void)n_in; (void)d_ws; (void)ws_size; (void)out_size;
  const float* scores = (const float*)d_in[0];
  float* out = (float*)d_out;
  float* out0   = out;                                                  // (32,800,5120)
  float* bwdo   = out + (size_t)NBATCH * T_STEPS * ROW;                 // (32,801,1024)
  float* fposts = bwdo + (size_t)NBATCH * (T_STEPS + 1) * SST;          // (32,801,1024)

  mega<<<2 * NBATCH, 256, 0, stream>>>(scores, out0, bwdo, fposts);
  posts_kernel<<<(NBATCH * (T_STEPS + 1)) / 4, 256, 0, stream>>>(fposts, bwdo);
}